// Round 17
// baseline (381.719 us; speedup 1.0000x reference)
//
#include <hip/hip_runtime.h>

// Block: LN1 -> per-head QKV -> causal attn -> proj+resid -> LN2 -> FF(relu)+resid
// B=4, T=2048, C=1024, H=16, HD=64.  All GEMMs bf16 MFMA (16x16x32), fp32 accum.
// FINAL CHAMPION (r12/r15, ~381us): gemm1p merged-phase 3-buf ring + attn_fwd2.

#define B_ 4
#define T_ 2048
#define C_ 1024
#define H_ 16
#define BT_ 8192

typedef __attribute__((ext_vector_type(8))) __bf16 bf16x8;
typedef __attribute__((ext_vector_type(4))) __bf16 bf16x4;
typedef __attribute__((ext_vector_type(4))) float f32x4;

#define WAIT_LGKM0 asm volatile("s_waitcnt lgkmcnt(0)" ::: "memory")
#define WAIT_VM(N) asm volatile("s_waitcnt vmcnt(" #N ")" ::: "memory")

__device__ __forceinline__ void gload_lds16(const void* g, void* l) {
  __builtin_amdgcn_global_load_lds((const __attribute__((address_space(1))) void*)g,
                                   (__attribute__((address_space(3))) void*)l, 16, 0, 0);
}

__device__ __forceinline__ void block_sync() {
  asm volatile("" ::: "memory");
  __builtin_amdgcn_s_barrier();
  asm volatile("" ::: "memory");
}

// ---------------- transpose fp32 [R][Cc] -> bf16 [Cc][R], batched ----------------
__global__ __launch_bounds__(256) void transpose_f32_bf16(
    const float* __restrict__ in, __bf16* __restrict__ out,
    int R, int Cc, long inBatch, long outBatch) {
  __shared__ float tile[32][33];
  const int tx = threadIdx.x, ty = threadIdx.y;
  in += (long)blockIdx.z * inBatch;
  out += (long)blockIdx.z * outBatch;
  const int r0 = blockIdx.y * 32, c0 = blockIdx.x * 32;
#pragma unroll
  for (int i = 0; i < 4; i++)
    tile[ty + i * 8][tx] = in[(long)(r0 + ty + i * 8) * Cc + c0 + tx];
  __syncthreads();
#pragma unroll
  for (int i = 0; i < 4; i++)
    out[(long)(c0 + ty + i * 8) * R + r0 + tx] = (__bf16)tile[tx][ty + i * 8];
}

// ---------------- LayerNorm: fp32 [rows][1024] -> bf16 ----------------
__global__ __launch_bounds__(256) void ln_fwd(const float* __restrict__ x,
                                              const float* __restrict__ g,
                                              const float* __restrict__ bta,
                                              __bf16* __restrict__ out) {
  const long row = blockIdx.x;
  const int tid = threadIdx.x;
  float4 v = ((const float4*)(x + row * C_))[tid];
  float vals[4] = {v.x, v.y, v.z, v.w};
  float s = vals[0] + vals[1] + vals[2] + vals[3];
  float s2 = vals[0] * vals[0] + vals[1] * vals[1] + vals[2] * vals[2] + vals[3] * vals[3];
#pragma unroll
  for (int o = 1; o < 64; o <<= 1) {
    s += __shfl_xor(s, o);
    s2 += __shfl_xor(s2, o);
  }
  __shared__ float red[8];
  const int lane = tid & 63, wid = tid >> 6;
  if (lane == 0) { red[wid] = s; red[wid + 4] = s2; }
  __syncthreads();
  const float S = red[0] + red[1] + red[2] + red[3];
  const float S2 = red[4] + red[5] + red[6] + red[7];
  const float mu = S * (1.0f / C_);
  const float var = S2 * (1.0f / C_) - mu * mu;
  const float rs = rsqrtf(var + 1e-5f);
  bf16x4 o4;
#pragma unroll
  for (int j = 0; j < 4; j++) {
    const int c = tid * 4 + j;
    o4[j] = (__bf16)((vals[j] - mu) * rs * g[c] + bta[c]);
  }
  *(bf16x4*)(out + row * C_ + tid * 4) = o4;
}

// ---------------- GEMM merged-phase: 128x256 tile, BK=64, ONE phase per K-tile ----------------
// A[M,K] x Bt[N,K]. 512 thr = 8 waves (2M x 4N), per-wave 64x64 (4rf x 4cf).
// Per phase: 16 ds_read_b128 + 6 gload_lds (tile u+2) + vmcnt(6) + barrier + lgkm0
// + 32 MFMA (setprio) + barrier. 3-buf ring (LDS 144KB): phase u reads buf u%3,
// stages tile u+2 into buf (u+2)%3. vmcnt(6) retires tile u+1. NT % 3 == 1.
// Swizzle chunk^=((row>>1)&3) on stage-source and ds_read (0 conflicts measured).
// EPI 0: bf16 bias+relu. EPI 1: QKV routing (V transposed). EPI 2: fp32 bias+resid.
template <int EPI>
__global__ __launch_bounds__(512, 2) void gemm1p(
    const __bf16* __restrict__ A, const __bf16* __restrict__ Bt,
    void* out0, void* out1, void* out2,
    const float* __restrict__ bias, const float* __restrict__ resid,
    int M, int N, int K, int nwg) {
  __shared__ __bf16 sm[73728];  // 144 KB: A 3x8192, B 3x16384
  __bf16* ldsA = &sm[0];
  __bf16* ldsB = &sm[24576];
  const int tid = threadIdx.x, lane = tid & 63, wid = tid >> 6;
  const int wm = wid >> 2, wn = wid & 3;
  const int l15 = lane & 15, qtr = lane >> 4;
  // bijective chunked XCD swizzle (nwg % 8 == 0); m-fast decode => XCD shares B-panel
  const int q8 = nwg >> 3;
  const int wg = (blockIdx.x & 7) * q8 + (blockIdx.x >> 3);
  const int mBlocks = M >> 7;
  const long mBase = (long)(wg % mBlocks) * 128;
  const long nBase = (long)(wg / mBlocks) * 256;
  const int NT = K >> 6;

  f32x4 acc[4][4] = {};

  // staging source (pre-swizzled global chunk): row = tid>>2, pos = tid&3
  const int spos = (tid & 3) ^ ((tid >> 3) & 3);
  const __bf16* aS = A + (mBase + (tid >> 2)) * (long)K + spos * 8;
  const __bf16* bS0 = Bt + (nBase + (tid >> 2)) * (long)K + spos * 8;
  const __bf16* bS1 = bS0 + 128 * (long)K;

  // fragment-read offsets (within a K-half)
  const int posRd = (qtr ^ ((l15 >> 1) & 3)) * 8;
  const int aRd = (wm * 64 + l15) * 32 + posRd;
  const int bRd = (wn * 64 + l15) * 32 + posRd;

// stage full tile KT (both K-halves) into ring buffer BUF: 6 loads
#define STG(BUF, KT)                                                                          \
  do {                                                                                        \
    gload_lds16(aS + (KT) * 64, ldsA + (BUF) * 8192 + tid * 8);                               \
    gload_lds16(aS + (KT) * 64 + 32, ldsA + (BUF) * 8192 + 4096 + tid * 8);                   \
    gload_lds16(bS0 + (KT) * 64, ldsB + (BUF) * 16384 + tid * 8);                             \
    gload_lds16(bS1 + (KT) * 64, ldsB + (BUF) * 16384 + 4096 + tid * 8);                      \
    gload_lds16(bS0 + (KT) * 64 + 32, ldsB + (BUF) * 16384 + 8192 + tid * 8);                 \
    gload_lds16(bS1 + (KT) * 64 + 32, ldsB + (BUF) * 16384 + 8192 + 4096 + tid * 8);          \
  } while (0)

#define GPHASE(BUF, VMN, ...)                                                              \
  do {                                                                                     \
    const __bf16* pA_ = &ldsA[(BUF) * 8192 + aRd];                                         \
    const __bf16* pB_ = &ldsB[(BUF) * 16384 + bRd];                                        \
    bf16x8 fa0 = *(const bf16x8*)&pA_[0];                                                  \
    bf16x8 fa1 = *(const bf16x8*)&pA_[512];                                                \
    bf16x8 fa2 = *(const bf16x8*)&pA_[1024];                                               \
    bf16x8 fa3 = *(const bf16x8*)&pA_[1536];                                               \
    bf16x8 fa4 = *(const bf16x8*)&pA_[4096];                                               \
    bf16x8 fa5 = *(const bf16x8*)&pA_[4608];                                               \
    bf16x8 fa6 = *(const bf16x8*)&pA_[5120];                                               \
    bf16x8 fa7 = *(const bf16x8*)&pA_[5632];                                               \
    bf16x8 fb0 = *(const bf16x8*)&pB_[0];                                                  \
    bf16x8 fb1 = *(const bf16x8*)&pB_[512];                                                \
    bf16x8 fb2 = *(const bf16x8*)&pB_[1024];                                               \
    bf16x8 fb3 = *(const bf16x8*)&pB_[1536];                                               \
    bf16x8 fb4 = *(const bf16x8*)&pB_[8192];                                               \
    bf16x8 fb5 = *(const bf16x8*)&pB_[8704];                                               \
    bf16x8 fb6 = *(const bf16x8*)&pB_[9216];                                               \
    bf16x8 fb7 = *(const bf16x8*)&pB_[9728];                                               \
    __VA_ARGS__;                                                                           \
    WAIT_VM(VMN);                                                                          \
    block_sync();                                                                          \
    WAIT_LGKM0;                                                                            \
    __builtin_amdgcn_sched_barrier(0);                                                     \
    __builtin_amdgcn_s_setprio(1);                                                         \
    acc[0][0] = __builtin_amdgcn_mfma_f32_16x16x32_bf16(fa0, fb0, acc[0][0], 0, 0, 0);     \
    acc[0][1] = __builtin_amdgcn_mfma_f32_16x16x32_bf16(fa0, fb1, acc[0][1], 0, 0, 0);     \
    acc[0][2] = __builtin_amdgcn_mfma_f32_16x16x32_bf16(fa0, fb2, acc[0][2], 0, 0, 0);     \
    acc[0][3] = __builtin_amdgcn_mfma_f32_16x16x32_bf16(fa0, fb3, acc[0][3], 0, 0, 0);     \
    acc[1][0] = __builtin_amdgcn_mfma_f32_16x16x32_bf16(fa1, fb0, acc[1][0], 0, 0, 0);     \
    acc[1][1] = __builtin_amdgcn_mfma_f32_16x16x32_bf16(fa1, fb1, acc[1][1], 0, 0, 0);     \
    acc[1][2] = __builtin_amdgcn_mfma_f32_16x16x32_bf16(fa1, fb2, acc[1][2], 0, 0, 0);     \
    acc[1][3] = __builtin_amdgcn_mfma_f32_16x16x32_bf16(fa1, fb3, acc[1][3], 0, 0, 0);     \
    acc[2][0] = __builtin_amdgcn_mfma_f32_16x16x32_bf16(fa2, fb0, acc[2][0], 0, 0, 0);     \
    acc[2][1] = __builtin_amdgcn_mfma_f32_16x16x32_bf16(fa2, fb1, acc[2][1], 0, 0, 0);     \
    acc[2][2] = __builtin_amdgcn_mfma_f32_16x16x32_bf16(fa2, fb2, acc[2][2], 0, 0, 0);     \
    acc[2][3] = __builtin_amdgcn_mfma_f32_16x16x32_bf16(fa2, fb3, acc[2][3], 0, 0, 0);     \
    acc[3][0] = __builtin_amdgcn_mfma_f32_16x16x32_bf16(fa3, fb0, acc[3][0], 0, 0, 0);     \
    acc[3][1] = __builtin_amdgcn_mfma_f32_16x16x32_bf16(fa3, fb1, acc[3][1], 0, 0, 0);     \
    acc[3][2] = __builtin_amdgcn_mfma_f32_16x16x32_bf16(fa3, fb2, acc[3][2], 0, 0, 0);     \
    acc[3][3] = __builtin_amdgcn_mfma_f32_16x16x32_bf16(fa3, fb3, acc[3][3], 0, 0, 0);     \
    acc[0][0] = __builtin_amdgcn_mfma_f32_16x16x32_bf16(fa4, fb4, acc[0][0], 0, 0, 0);     \
    acc[0][1] = __builtin_amdgcn_mfma_f32_16x16x32_bf16(fa4, fb5, acc[0][1], 0, 0, 0);     \
    acc[0][2] = __builtin_amdgcn_mfma_f32_16x16x32_bf16(fa4, fb6, acc[0][2], 0, 0, 0);     \
    acc[0][3] = __builtin_amdgcn_mfma_f32_16x16x32_bf16(fa4, fb7, acc[0][3], 0, 0, 0);     \
    acc[1][0] = __builtin_amdgcn_mfma_f32_16x16x32_bf16(fa5, fb4, acc[1][0], 0, 0, 0);     \
    acc[1][1] = __builtin_amdgcn_mfma_f32_16x16x32_bf16(fa5, fb5, acc[1][1], 0, 0, 0);     \
    acc[1][2] = __builtin_amdgcn_mfma_f32_16x16x32_bf16(fa5, fb6, acc[1][2], 0, 0, 0);     \
    acc[1][3] = __builtin_amdgcn_mfma_f32_16x16x32_bf16(fa5, fb7, acc[1][3], 0, 0, 0);     \
    acc[2][0] = __builtin_amdgcn_mfma_f32_16x16x32_bf16(fa6, fb4, acc[2][0], 0, 0, 0);     \
    acc[2][1] = __builtin_amdgcn_mfma_f32_16x16x32_bf16(fa6, fb5, acc[2][1], 0, 0, 0);     \
    acc[2][2] = __builtin_amdgcn_mfma_f32_16x16x32_bf16(fa6, fb6, acc[2][2], 0, 0, 0);     \
    acc[2][3] = __builtin_amdgcn_mfma_f32_16x16x32_bf16(fa6, fb7, acc[2][3], 0, 0, 0);     \
    acc[3][0] = __builtin_amdgcn_mfma_f32_16x16x32_bf16(fa7, fb4, acc[3][0], 0, 0, 0);     \
    acc[3][1] = __builtin_amdgcn_mfma_f32_16x16x32_bf16(fa7, fb5, acc[3][1], 0, 0, 0);     \
    acc[3][2] = __builtin_amdgcn_mfma_f32_16x16x32_bf16(fa7, fb6, acc[3][2], 0, 0, 0);     \
    acc[3][3] = __builtin_amdgcn_mfma_f32_16x16x32_bf16(fa7, fb7, acc[3][3], 0, 0, 0);     \
    __builtin_amdgcn_s_setprio(0);                                                         \
    block_sync();                                                                          \
  } while (0)

  // prologue: stage tiles 0,1 (12 loads); retire tile 0
  STG(0, 0);
  STG(1, 1);
  WAIT_VM(6);
  block_sync();

  // main: phase u reads buf u%3, stages tile u+2 into (u+2)%3, vmcnt(6) retires u+1
  int b = 0;
  for (int u = 0; u < NT - 2; ++u) {
    const int bnx = (b + 2 >= 3) ? b - 1 : b + 2;
    GPHASE(b, 6, STG(bnx, u + 2));
    b = (b + 1 == 3) ? 0 : b + 1;
  }
  // tail (NT % 3 == 1): tile NT-2 in buf 2, tile NT-1 in buf 0
  GPHASE(2, 0, );
  GPHASE(0, 0, );

#undef GPHASE
#undef STG

  // ---- epilogue
  if (EPI == 0) {
    __bf16* outB = (__bf16*)out0;
#pragma unroll
    for (int cf = 0; cf < 4; cf++) {
      const long gc = nBase + wn * 64 + cf * 16 + l15;
      const float bv = bias[gc];
#pragma unroll
      for (int rf = 0; rf < 4; rf++) {
        const long gr0 = mBase + wm * 64 + rf * 16 + qtr * 4;
#pragma unroll
        for (int r = 0; r < 4; r++)
          outB[(gr0 + r) * (long)N + gc] = (__bf16)fmaxf(acc[rf][cf][r] + bv, 0.0f);
      }
    }
  } else if (EPI == 2) {
    float* outF = (float*)out0;
#pragma unroll
    for (int cf = 0; cf < 4; cf++) {
      const long gc = nBase + wn * 64 + cf * 16 + l15;
      const float bv = bias[gc];
#pragma unroll
      for (int rf = 0; rf < 4; rf++) {
        const long gr0 = mBase + wm * 64 + rf * 16 + qtr * 4;
#pragma unroll
        for (int r = 0; r < 4; r++)
          outF[(gr0 + r) * (long)N + gc] = acc[rf][cf][r] + bv + resid[(gr0 + r) * (long)N + gc];
      }
    }
  } else {
    // QKV routing: seg 0 -> Q [BT,1024], 1 -> K [BT,1024], 2 -> V transposed [1024][BT]
    const int seg = (int)(nBase >> 10);
#pragma unroll
    for (int cf = 0; cf < 4; cf++) {
      const long gc = nBase + wn * 64 + cf * 16 + l15;
      const long cc = gc & 1023;
#pragma unroll
      for (int rf = 0; rf < 4; rf++) {
        const long gr0 = mBase + wm * 64 + rf * 16 + qtr * 4;
        if (seg == 0) {
          __bf16* Qb = (__bf16*)out0;
#pragma unroll
          for (int r = 0; r < 4; r++) Qb[(gr0 + r) * 1024 + cc] = (__bf16)acc[rf][cf][r];
        } else if (seg == 1) {
          __bf16* Kb = (__bf16*)out1;
#pragma unroll
          for (int r = 0; r < 4; r++) Kb[(gr0 + r) * 1024 + cc] = (__bf16)acc[rf][cf][r];
        } else {
          __bf16* Vtg = (__bf16*)out2;
          bf16x4 v4;
#pragma unroll
          for (int r = 0; r < 4; r++) v4[r] = (__bf16)acc[rf][cf][r];
          *(bf16x4*)&Vtg[cc * (long)BT_ + gr0] = v4;
        }
      }
    }
  }
}

// ---------------- causal flash attention v2 (champion) ----------------
#define PSTR 72
__global__ __launch_bounds__(512, 6) void attn_fwd2(
    const __bf16* __restrict__ Qg, const __bf16* __restrict__ Kg,
    const __bf16* __restrict__ Vtg, __bf16* __restrict__ O) {
  __shared__ __bf16 Ks[2][64 * 64];
  __shared__ __bf16 Vs[2][64 * 64];
  __shared__ __bf16 Ps[128 * PSTR];
  const int tid = threadIdx.x, lane = tid & 63, wid = tid >> 6;
  const int bh = blockIdx.x, b = bh >> 4, h = bh & 15;
  const int qx = 15 - blockIdx.y;           // heavy blocks first
  const int qBase = qx * 128;
  const int qw = qBase + wid * 16;
  const int qwTop = qw + 15;
  const long bT = (long)b * T_;
  const int l15 = lane & 15, qtr = lane >> 4;
  const int q_lane = qw + l15;

  const int srow = tid >> 3;
  const int schunk = (tid & 7) ^ (srow & 7);
  const __bf16* kSrcBase = Kg + (bT + srow) * C_ + h * 64 + schunk * 8;
  const __bf16* vSrcBase = Vtg + (long)(h * 64 + srow) * BT_ + bT + schunk * 8;
  __bf16* kDst = &Ks[0][tid * 8];
  __bf16* vDst = &Vs[0][tid * 8];
  const int bufStride = 64 * 64;

  __bf16* psW = &Ps[(wid * 16 + l15) * PSTR + qtr * 4];
  const __bf16* psR = &Ps[(wid * 16 + l15) * PSTR + qtr * 8];

  bf16x8 q0s, q1s;
  {
    const float SC = 0.125f * 1.44269504089f;  // 1/sqrt(64) * log2(e)
    bf16x8 r0 = *(const bf16x8*)(Qg + (bT + q_lane) * C_ + h * 64 + qtr * 8);
    bf16x8 r1 = *(const bf16x8*)(Qg + (bT + q_lane) * C_ + h * 64 + 32 + qtr * 8);
#pragma unroll
    for (int j = 0; j < 8; j++) {
      q0s[j] = (__bf16)((float)r0[j] * SC);
      q1s[j] = (__bf16)((float)r1[j] * SC);
    }
  }

  f32x4 o[4] = {};
  float m_ = -1e30f, l_ = 0.0f;
  const int nkt = 2 * qx + 2;

  gload_lds16(kSrcBase, kDst);
  gload_lds16(vSrcBase, vDst);
  __syncthreads();

  int buf = 0;
  for (int t = 0; t < nkt; t++) {
    const int k0 = t * 64;
    if (t + 1 < nkt) {
      const long koff = (long)(k0 + 64);
      gload_lds16(kSrcBase + koff * C_, kDst + (buf ^ 1) * bufStride);
      gload_lds16(vSrcBase + koff, vDst + (buf ^ 1) * bufStride);
    }
    if (k0 <= qwTop) {
      const __bf16* ks = Ks[buf];
      const __bf16* vs = Vs[buf];
      f32x4 sT[4] = {};
      __builtin_amdgcn_s_setprio(1);
#pragma unroll
      for (int kb = 0; kb < 4; kb++) {
        bf16x8 aK0 = *(const bf16x8*)&ks[(kb * 16 + l15) * 64 + ((qtr ^ (l15 & 7)) * 8)];
        bf16x8 aK1 = *(const bf16x8*)&ks[(kb * 16 + l15) * 64 + (((4 + qtr) ^ (l15 & 7)) * 8)];
        sT[kb] = __builtin_amdgcn_mfma_f32_16x16x32_bf16(aK0, q0s, sT[kb], 0, 0, 0);
        sT[kb] = __builtin_amdgcn_mfma_f32_16x16x32_bf16(aK1, q1s, sT[kb], 0, 0, 0);
      }
      __builtin_amdgcn_s_setprio(0);
      if (k0 + 63 > qw) {
#pragma unroll
        for (int kb = 0; kb < 4; kb++)
#pragma unroll
          for (int r = 0; r < 4; r++)
            if (k0 + kb * 16 + qtr * 4 + r > q_lane) sT[kb][r] = -1e30f;
      }
      float mx = -1e30f;
#pragma unroll
      for (int kb = 0; kb < 4; kb++)
#pragma unroll
        for (int r = 0; r < 4; r++) mx = fmaxf(mx, sT[kb][r]);
      mx = fmaxf(mx, __shfl_xor(mx, 16));
      mx = fmaxf(mx, __shfl_xor(mx, 32));
      const bool defer = __all(mx - m_ <= 8.0f);
      const float mnew = defer ? m_ : fmaxf(m_, mx);
      float psum = 0.0f;
#pragma unroll
      for (int kb = 0; kb < 4; kb++) {
        bf16x4 p4;
#pragma unroll
        for (int r = 0; r < 4; r++) {
          const float pv = exp2f(sT[kb][r] - mnew);
          psum += pv;
          p4[r] = (__bf16)pv;
        }
        *(bf16x4*)&psW[kb * 16] = p4;
      }
      psum += __shfl_xor(psum, 16);
      psum += __shfl_xor(psum, 32);
      if (defer) {
        l_ += psum;
      } else {
        const float fac = exp2f(m_ - mnew);
        l_ = l_ * fac + psum;
        m_ = mnew;
#pragma unroll
        for (int r = 0; r < 4; r++) {
          const float fr = __shfl(fac, (lane & 48) + qtr * 4 + r);
#pragma unroll
          for (int dg = 0; dg < 4; dg++) o[dg][r] *= fr;
        }
      }
      __builtin_amdgcn_s_setprio(1);
#pragma unroll
      for (int s = 0; s < 2; s++) {
        bf16x8 aP = *(const bf16x8*)&psR[s * 32];
#pragma unroll
        for (int dg = 0; dg < 4; dg++) {
          bf16x8 bV = *(const bf16x8*)&vs[(dg * 16 + l15) * 64 + (((s * 4 + qtr) ^ (l15 & 7)) * 8)];
          o[dg] = __builtin_amdgcn_mfma_f32_16x16x32_bf16(aP, bV, o[dg], 0, 0, 0);
        }
      }
      __builtin_amdgcn_s_setprio(0);
    }
    __syncthreads();
    buf ^= 1;
  }

  const float linv = 1.0f / l_;
#pragma unroll
  for (int r = 0; r < 4; r++) {
    const float lr = __shfl(linv, (lane & 48) + qtr * 4 + r);
    const long row = bT + qw + qtr * 4 + r;
#pragma unroll
    for (int dg = 0; dg < 4; dg++)
      O[row * C_ + h * 64 + dg * 16 + l15] = (__bf16)(o[dg][r] * lr);
  }
}

// ---------------- launch ----------------
extern "C" void kernel_launch(void* const* d_in, const int* in_sizes, int n_in,
                              void* d_out, int out_size, void* d_ws, size_t ws_size,
                              hipStream_t stream) {
  const float* x = (const float*)d_in[0];
  const float* wq = (const float*)d_in[1];
  const float* wk = (const float*)d_in[2];
  const float* wv = (const float*)d_in[3];
  const float* wproj = (const float*)d_in[4];
  const float* bproj = (const float*)d_in[5];
  const float* w1 = (const float*)d_in[6];
  const float* b1 = (const float*)d_in[7];
  const float* w2 = (const float*)d_in[8];
  const float* b2 = (const float*)d_in[9];
  const float* g1 = (const float*)d_in[10];
  const float* be1 = (const float*)d_in[11];
  const float* g2 = (const float*)d_in[12];
  const float* be2 = (const float*)d_in[13];

  char* ws = (char*)d_ws;
  const size_t MB = 1024ull * 1024ull;
  __bf16* h1 = (__bf16*)(ws + 0);          // 16MB; reused as att after QKV
  __bf16* Qb = (__bf16*)(ws + 16 * MB);    // 16MB; reused as h2 after attn
  __bf16* Kb = (__bf16*)(ws + 32 * MB);    // 16MB
  __bf16* Vtg = (__bf16*)(ws + 48 * MB);   // 16MB, V pre-transposed [C][B*T]
  __bf16* ff1 = (__bf16*)(ws + 32 * MB);   // 64MB, aliases Kb/Vtg (dead after attn)
  __bf16* wqt = (__bf16*)(ws + 96 * MB);   // wqt/wkt/wvt contiguous => [3072][1024]
  __bf16* wkt = (__bf16*)(ws + 98 * MB);
  __bf16* wvt = (__bf16*)(ws + 100 * MB);
  __bf16* wpt = (__bf16*)(ws + 102 * MB);
  __bf16* w1t = (__bf16*)(ws + 104 * MB);  // 8MB
  __bf16* w2t = (__bf16*)(ws + 112 * MB);  // 8MB
  __bf16* att = h1;
  __bf16* h2 = Qb;
  float* xout = (float*)d_out;

  dim3 tb(32, 8);
  transpose_f32_bf16<<<dim3(2, 32, 16), tb, 0, stream>>>(wq, wqt, 1024, 64, 1024 * 64, 64 * 1024);
  transpose_f32_bf16<<<dim3(2, 32, 16), tb, 0, stream>>>(wk, wkt, 1024, 64, 1024 * 64, 64 * 1024);
  transpose_f32_bf16<<<dim3(2, 32, 16), tb, 0, stream>>>(wv, wvt, 1024, 64, 1024 * 64, 64 * 1024);
  transpose_f32_bf16<<<dim3(32, 32, 1), tb, 0, stream>>>(wproj, wpt, 1024, 1024, 0, 0);
  transpose_f32_bf16<<<dim3(128, 32, 1), tb, 0, stream>>>(w1, w1t, 1024, 4096, 0, 0);
  transpose_f32_bf16<<<dim3(32, 128, 1), tb, 0, stream>>>(w2, w2t, 4096, 1024, 0, 0);

  ln_fwd<<<8192, 256, 0, stream>>>(x, g1, be1, h1);
  // fused QKV: Bt = [wqt|wkt|wvt] = [3072][1024]; 64 m-blocks x 12 n-blocks
  gemm1p<1><<<768, 512, 0, stream>>>(h1, wqt, Qb, Kb, Vtg, nullptr, nullptr, 8192, 3072, 1024, 768);
  attn_fwd2<<<dim3(64, 16), 512, 0, stream>>>(Qb, Kb, Vtg, att);
  gemm1p<2><<<256, 512, 0, stream>>>(att, wpt, xout, nullptr, nullptr, bproj, x, 8192, 1024, 1024, 256);
  ln_fwd<<<8192, 256, 0, stream>>>(xout, g2, be2, h2);
  gemm1p<0><<<1024, 512, 0, stream>>>(h2, w1t, ff1, nullptr, nullptr, b1, nullptr, 8192, 4096, 1024, 1024);
  gemm1p<2><<<256, 512, 0, stream>>>(ff1, w2t, xout, nullptr, nullptr, b2, (const float*)xout, 8192, 1024, 4096, 256);
}

// Round 18
// 380.046 us; speedup vs baseline: 1.0044x; 1.0044x over previous
//
#include <hip/hip_runtime.h>

// Block: LN1 -> per-head QKV -> causal attn -> proj+resid -> LN2 -> FF(relu)+resid
// B=4, T=2048, C=1024, H=16, HD=64.  All GEMMs bf16 MFMA (16x16x32), fp32 accum.
// r17: gemm1p WITHOUT explicit lgkm0+sched_barrier (let compiler fine-schedule
// ds_read->MFMA waits, per m97/m141 evidence). Everything else = champion.

#define B_ 4
#define T_ 2048
#define C_ 1024
#define H_ 16
#define BT_ 8192

typedef __attribute__((ext_vector_type(8))) __bf16 bf16x8;
typedef __attribute__((ext_vector_type(4))) __bf16 bf16x4;
typedef __attribute__((ext_vector_type(4))) float f32x4;

#define WAIT_VM(N) asm volatile("s_waitcnt vmcnt(" #N ")" ::: "memory")

__device__ __forceinline__ void gload_lds16(const void* g, void* l) {
  __builtin_amdgcn_global_load_lds((const __attribute__((address_space(1))) void*)g,
                                   (__attribute__((address_space(3))) void*)l, 16, 0, 0);
}

__device__ __forceinline__ void block_sync() {
  asm volatile("" ::: "memory");
  __builtin_amdgcn_s_barrier();
  asm volatile("" ::: "memory");
}

// ---------------- transpose fp32 [R][Cc] -> bf16 [Cc][R], batched ----------------
__global__ __launch_bounds__(256) void transpose_f32_bf16(
    const float* __restrict__ in, __bf16* __restrict__ out,
    int R, int Cc, long inBatch, long outBatch) {
  __shared__ float tile[32][33];
  const int tx = threadIdx.x, ty = threadIdx.y;
  in += (long)blockIdx.z * inBatch;
  out += (long)blockIdx.z * outBatch;
  const int r0 = blockIdx.y * 32, c0 = blockIdx.x * 32;
#pragma unroll
  for (int i = 0; i < 4; i++)
    tile[ty + i * 8][tx] = in[(long)(r0 + ty + i * 8) * Cc + c0 + tx];
  __syncthreads();
#pragma unroll
  for (int i = 0; i < 4; i++)
    out[(long)(c0 + ty + i * 8) * R + r0 + tx] = (__bf16)tile[tx][ty + i * 8];
}

// ---------------- LayerNorm: fp32 [rows][1024] -> bf16 ----------------
__global__ __launch_bounds__(256) void ln_fwd(const float* __restrict__ x,
                                              const float* __restrict__ g,
                                              const float* __restrict__ bta,
                                              __bf16* __restrict__ out) {
  const long row = blockIdx.x;
  const int tid = threadIdx.x;
  float4 v = ((const float4*)(x + row * C_))[tid];
  float vals[4] = {v.x, v.y, v.z, v.w};
  float s = vals[0] + vals[1] + vals[2] + vals[3];
  float s2 = vals[0] * vals[0] + vals[1] * vals[1] + vals[2] * vals[2] + vals[3] * vals[3];
#pragma unroll
  for (int o = 1; o < 64; o <<= 1) {
    s += __shfl_xor(s, o);
    s2 += __shfl_xor(s2, o);
  }
  __shared__ float red[8];
  const int lane = tid & 63, wid = tid >> 6;
  if (lane == 0) { red[wid] = s; red[wid + 4] = s2; }
  __syncthreads();
  const float S = red[0] + red[1] + red[2] + red[3];
  const float S2 = red[4] + red[5] + red[6] + red[7];
  const float mu = S * (1.0f / C_);
  const float var = S2 * (1.0f / C_) - mu * mu;
  const float rs = rsqrtf(var + 1e-5f);
  bf16x4 o4;
#pragma unroll
  for (int j = 0; j < 4; j++) {
    const int c = tid * 4 + j;
    o4[j] = (__bf16)((vals[j] - mu) * rs * g[c] + bta[c]);
  }
  *(bf16x4*)(out + row * C_ + tid * 4) = o4;
}

// ---------------- GEMM merged-phase: 128x256 tile, BK=64, ONE phase per K-tile ----------------
// A[M,K] x Bt[N,K]. 512 thr = 8 waves (2M x 4N), per-wave 64x64 (4rf x 4cf).
// Per phase: 16 ds_read_b128 + 6 gload_lds (tile u+2) + vmcnt(6) + barrier +
// 32 MFMA (setprio; compiler emits fine-grained lgkmcnt for ds_read->MFMA) + barrier.
// 3-buf ring (LDS 144KB): phase u reads buf u%3, stages tile u+2 into buf (u+2)%3.
// vmcnt(6) retires tile u+1. NT % 3 == 1. Swizzle chunk^=((row>>1)&3) both sides.
// EPI 0: bf16 bias+relu. EPI 1: QKV routing (V transposed). EPI 2: fp32 bias+resid.
template <int EPI>
__global__ __launch_bounds__(512, 2) void gemm1p(
    const __bf16* __restrict__ A, const __bf16* __restrict__ Bt,
    void* out0, void* out1, void* out2,
    const float* __restrict__ bias, const float* __restrict__ resid,
    int M, int N, int K, int nwg) {
  __shared__ __bf16 sm[73728];  // 144 KB: A 3x8192, B 3x16384
  __bf16* ldsA = &sm[0];
  __bf16* ldsB = &sm[24576];
  const int tid = threadIdx.x, lane = tid & 63, wid = tid >> 6;
  const int wm = wid >> 2, wn = wid & 3;
  const int l15 = lane & 15, qtr = lane >> 4;
  // bijective chunked XCD swizzle (nwg % 8 == 0); m-fast decode => XCD shares B-panel
  const int q8 = nwg >> 3;
  const int wg = (blockIdx.x & 7) * q8 + (blockIdx.x >> 3);
  const int mBlocks = M >> 7;
  const long mBase = (long)(wg % mBlocks) * 128;
  const long nBase = (long)(wg / mBlocks) * 256;
  const int NT = K >> 6;

  f32x4 acc[4][4] = {};

  // staging source (pre-swizzled global chunk): row = tid>>2, pos = tid&3
  const int spos = (tid & 3) ^ ((tid >> 3) & 3);
  const __bf16* aS = A + (mBase + (tid >> 2)) * (long)K + spos * 8;
  const __bf16* bS0 = Bt + (nBase + (tid >> 2)) * (long)K + spos * 8;
  const __bf16* bS1 = bS0 + 128 * (long)K;

  // fragment-read offsets (within a K-half)
  const int posRd = (qtr ^ ((l15 >> 1) & 3)) * 8;
  const int aRd = (wm * 64 + l15) * 32 + posRd;
  const int bRd = (wn * 64 + l15) * 32 + posRd;

// stage full tile KT (both K-halves) into ring buffer BUF: 6 loads
#define STG(BUF, KT)                                                                          \
  do {                                                                                        \
    gload_lds16(aS + (KT) * 64, ldsA + (BUF) * 8192 + tid * 8);                               \
    gload_lds16(aS + (KT) * 64 + 32, ldsA + (BUF) * 8192 + 4096 + tid * 8);                   \
    gload_lds16(bS0 + (KT) * 64, ldsB + (BUF) * 16384 + tid * 8);                             \
    gload_lds16(bS1 + (KT) * 64, ldsB + (BUF) * 16384 + 4096 + tid * 8);                      \
    gload_lds16(bS0 + (KT) * 64 + 32, ldsB + (BUF) * 16384 + 8192 + tid * 8);                 \
    gload_lds16(bS1 + (KT) * 64 + 32, ldsB + (BUF) * 16384 + 8192 + 4096 + tid * 8);          \
  } while (0)

#define GPHASE(BUF, VMN, ...)                                                              \
  do {                                                                                     \
    const __bf16* pA_ = &ldsA[(BUF) * 8192 + aRd];                                         \
    const __bf16* pB_ = &ldsB[(BUF) * 16384 + bRd];                                        \
    bf16x8 fa0 = *(const bf16x8*)&pA_[0];                                                  \
    bf16x8 fa1 = *(const bf16x8*)&pA_[512];                                                \
    bf16x8 fa2 = *(const bf16x8*)&pA_[1024];                                               \
    bf16x8 fa3 = *(const bf16x8*)&pA_[1536];                                               \
    bf16x8 fa4 = *(const bf16x8*)&pA_[4096];                                               \
    bf16x8 fa5 = *(const bf16x8*)&pA_[4608];                                               \
    bf16x8 fa6 = *(const bf16x8*)&pA_[5120];                                               \
    bf16x8 fa7 = *(const bf16x8*)&pA_[5632];                                               \
    bf16x8 fb0 = *(const bf16x8*)&pB_[0];                                                  \
    bf16x8 fb1 = *(const bf16x8*)&pB_[512];                                                \
    bf16x8 fb2 = *(const bf16x8*)&pB_[1024];                                               \
    bf16x8 fb3 = *(const bf16x8*)&pB_[1536];                                               \
    bf16x8 fb4 = *(const bf16x8*)&pB_[8192];                                               \
    bf16x8 fb5 = *(const bf16x8*)&pB_[8704];                                               \
    bf16x8 fb6 = *(const bf16x8*)&pB_[9216];                                               \
    bf16x8 fb7 = *(const bf16x8*)&pB_[9728];                                               \
    __VA_ARGS__;                                                                           \
    WAIT_VM(VMN);                                                                          \
    block_sync();                                                                          \
    __builtin_amdgcn_s_setprio(1);                                                         \
    acc[0][0] = __builtin_amdgcn_mfma_f32_16x16x32_bf16(fa0, fb0, acc[0][0], 0, 0, 0);     \
    acc[0][1] = __builtin_amdgcn_mfma_f32_16x16x32_bf16(fa0, fb1, acc[0][1], 0, 0, 0);     \
    acc[0][2] = __builtin_amdgcn_mfma_f32_16x16x32_bf16(fa0, fb2, acc[0][2], 0, 0, 0);     \
    acc[0][3] = __builtin_amdgcn_mfma_f32_16x16x32_bf16(fa0, fb3, acc[0][3], 0, 0, 0);     \
    acc[1][0] = __builtin_amdgcn_mfma_f32_16x16x32_bf16(fa1, fb0, acc[1][0], 0, 0, 0);     \
    acc[1][1] = __builtin_amdgcn_mfma_f32_16x16x32_bf16(fa1, fb1, acc[1][1], 0, 0, 0);     \
    acc[1][2] = __builtin_amdgcn_mfma_f32_16x16x32_bf16(fa1, fb2, acc[1][2], 0, 0, 0);     \
    acc[1][3] = __builtin_amdgcn_mfma_f32_16x16x32_bf16(fa1, fb3, acc[1][3], 0, 0, 0);     \
    acc[2][0] = __builtin_amdgcn_mfma_f32_16x16x32_bf16(fa2, fb0, acc[2][0], 0, 0, 0);     \
    acc[2][1] = __builtin_amdgcn_mfma_f32_16x16x32_bf16(fa2, fb1, acc[2][1], 0, 0, 0);     \
    acc[2][2] = __builtin_amdgcn_mfma_f32_16x16x32_bf16(fa2, fb2, acc[2][2], 0, 0, 0);     \
    acc[2][3] = __builtin_amdgcn_mfma_f32_16x16x32_bf16(fa2, fb3, acc[2][3], 0, 0, 0);     \
    acc[3][0] = __builtin_amdgcn_mfma_f32_16x16x32_bf16(fa3, fb0, acc[3][0], 0, 0, 0);     \
    acc[3][1] = __builtin_amdgcn_mfma_f32_16x16x32_bf16(fa3, fb1, acc[3][1], 0, 0, 0);     \
    acc[3][2] = __builtin_amdgcn_mfma_f32_16x16x32_bf16(fa3, fb2, acc[3][2], 0, 0, 0);     \
    acc[3][3] = __builtin_amdgcn_mfma_f32_16x16x32_bf16(fa3, fb3, acc[3][3], 0, 0, 0);     \
    acc[0][0] = __builtin_amdgcn_mfma_f32_16x16x32_bf16(fa4, fb4, acc[0][0], 0, 0, 0);     \
    acc[0][1] = __builtin_amdgcn_mfma_f32_16x16x32_bf16(fa4, fb5, acc[0][1], 0, 0, 0);     \
    acc[0][2] = __builtin_amdgcn_mfma_f32_16x16x32_bf16(fa4, fb6, acc[0][2], 0, 0, 0);     \
    acc[0][3] = __builtin_amdgcn_mfma_f32_16x16x32_bf16(fa4, fb7, acc[0][3], 0, 0, 0);     \
    acc[1][0] = __builtin_amdgcn_mfma_f32_16x16x32_bf16(fa5, fb4, acc[1][0], 0, 0, 0);     \
    acc[1][1] = __builtin_amdgcn_mfma_f32_16x16x32_bf16(fa5, fb5, acc[1][1], 0, 0, 0);     \
    acc[1][2] = __builtin_amdgcn_mfma_f32_16x16x32_bf16(fa5, fb6, acc[1][2], 0, 0, 0);     \
    acc[1][3] = __builtin_amdgcn_mfma_f32_16x16x32_bf16(fa5, fb7, acc[1][3], 0, 0, 0);     \
    acc[2][0] = __builtin_amdgcn_mfma_f32_16x16x32_bf16(fa6, fb4, acc[2][0], 0, 0, 0);     \
    acc[2][1] = __builtin_amdgcn_mfma_f32_16x16x32_bf16(fa6, fb5, acc[2][1], 0, 0, 0);     \
    acc[2][2] = __builtin_amdgcn_mfma_f32_16x16x32_bf16(fa6, fb6, acc[2][2], 0, 0, 0);     \
    acc[2][3] = __builtin_amdgcn_mfma_f32_16x16x32_bf16(fa6, fb7, acc[2][3], 0, 0, 0);     \
    acc[3][0] = __builtin_amdgcn_mfma_f32_16x16x32_bf16(fa7, fb4, acc[3][0], 0, 0, 0);     \
    acc[3][1] = __builtin_amdgcn_mfma_f32_16x16x32_bf16(fa7, fb5, acc[3][1], 0, 0, 0);     \
    acc[3][2] = __builtin_amdgcn_mfma_f32_16x16x32_bf16(fa7, fb6, acc[3][2], 0, 0, 0);     \
    acc[3][3] = __builtin_amdgcn_mfma_f32_16x16x32_bf16(fa7, fb7, acc[3][3], 0, 0, 0);     \
    __builtin_amdgcn_s_setprio(0);                                                         \
    block_sync();                                                                          \
  } while (0)

  // prologue: stage tiles 0,1 (12 loads); retire tile 0
  STG(0, 0);
  STG(1, 1);
  WAIT_VM(6);
  block_sync();

  // main: phase u reads buf u%3, stages tile u+2 into (u+2)%3, vmcnt(6) retires u+1
  int b = 0;
  for (int u = 0; u < NT - 2; ++u) {
    const int bnx = (b + 2 >= 3) ? b - 1 : b + 2;
    GPHASE(b, 6, STG(bnx, u + 2));
    b = (b + 1 == 3) ? 0 : b + 1;
  }
  // tail (NT % 3 == 1): tile NT-2 in buf 2, tile NT-1 in buf 0
  GPHASE(2, 0, );
  GPHASE(0, 0, );

#undef GPHASE
#undef STG

  // ---- epilogue
  if (EPI == 0) {
    __bf16* outB = (__bf16*)out0;
#pragma unroll
    for (int cf = 0; cf < 4; cf++) {
      const long gc = nBase + wn * 64 + cf * 16 + l15;
      const float bv = bias[gc];
#pragma unroll
      for (int rf = 0; rf < 4; rf++) {
        const long gr0 = mBase + wm * 64 + rf * 16 + qtr * 4;
#pragma unroll
        for (int r = 0; r < 4; r++)
          outB[(gr0 + r) * (long)N + gc] = (__bf16)fmaxf(acc[rf][cf][r] + bv, 0.0f);
      }
    }
  } else if (EPI == 2) {
    float* outF = (float*)out0;
#pragma unroll
    for (int cf = 0; cf < 4; cf++) {
      const long gc = nBase + wn * 64 + cf * 16 + l15;
      const float bv = bias[gc];
#pragma unroll
      for (int rf = 0; rf < 4; rf++) {
        const long gr0 = mBase + wm * 64 + rf * 16 + qtr * 4;
#pragma unroll
        for (int r = 0; r < 4; r++)
          outF[(gr0 + r) * (long)N + gc] = acc[rf][cf][r] + bv + resid[(gr0 + r) * (long)N + gc];
      }
    }
  } else {
    // QKV routing: seg 0 -> Q [BT,1024], 1 -> K [BT,1024], 2 -> V transposed [1024][BT]
    const int seg = (int)(nBase >> 10);
#pragma unroll
    for (int cf = 0; cf < 4; cf++) {
      const long gc = nBase + wn * 64 + cf * 16 + l15;
      const long cc = gc & 1023;
#pragma unroll
      for (int rf = 0; rf < 4; rf++) {
        const long gr0 = mBase + wm * 64 + rf * 16 + qtr * 4;
        if (seg == 0) {
          __bf16* Qb = (__bf16*)out0;
#pragma unroll
          for (int r = 0; r < 4; r++) Qb[(gr0 + r) * 1024 + cc] = (__bf16)acc[rf][cf][r];
        } else if (seg == 1) {
          __bf16* Kb = (__bf16*)out1;
#pragma unroll
          for (int r = 0; r < 4; r++) Kb[(gr0 + r) * 1024 + cc] = (__bf16)acc[rf][cf][r];
        } else {
          __bf16* Vtg = (__bf16*)out2;
          bf16x4 v4;
#pragma unroll
          for (int r = 0; r < 4; r++) v4[r] = (__bf16)acc[rf][cf][r];
          *(bf16x4*)&Vtg[cc * (long)BT_ + gr0] = v4;
        }
      }
    }
  }
}

// ---------------- causal flash attention v2 (champion) ----------------
#define PSTR 72
__global__ __launch_bounds__(512, 6) void attn_fwd2(
    const __bf16* __restrict__ Qg, const __bf16* __restrict__ Kg,
    const __bf16* __restrict__ Vtg, __bf16* __restrict__ O) {
  __shared__ __bf16 Ks[2][64 * 64];
  __shared__ __bf16 Vs[2][64 * 64];
  __shared__ __bf16 Ps[128 * PSTR];
  const int tid = threadIdx.x, lane = tid & 63, wid = tid >> 6;
  const int bh = blockIdx.x, b = bh >> 4, h = bh & 15;
  const int qx = 15 - blockIdx.y;           // heavy blocks first
  const int qBase = qx * 128;
  const int qw = qBase + wid * 16;
  const int qwTop = qw + 15;
  const long bT = (long)b * T_;
  const int l15 = lane & 15, qtr = lane >> 4;
  const int q_lane = qw + l15;

  const int srow = tid >> 3;
  const int schunk = (tid & 7) ^ (srow & 7);
  const __bf16* kSrcBase = Kg + (bT + srow) * C_ + h * 64 + schunk * 8;
  const __bf16* vSrcBase = Vtg + (long)(h * 64 + srow) * BT_ + bT + schunk * 8;
  __bf16* kDst = &Ks[0][tid * 8];
  __bf16* vDst = &Vs[0][tid * 8];
  const int bufStride = 64 * 64;

  __bf16* psW = &Ps[(wid * 16 + l15) * PSTR + qtr * 4];
  const __bf16* psR = &Ps[(wid * 16 + l15) * PSTR + qtr * 8];

  bf16x8 q0s, q1s;
  {
    const float SC = 0.125f * 1.44269504089f;  // 1/sqrt(64) * log2(e)
    bf16x8 r0 = *(const bf16x8*)(Qg + (bT + q_lane) * C_ + h * 64 + qtr * 8);
    bf16x8 r1 = *(const bf16x8*)(Qg + (bT + q_lane) * C_ + h * 64 + 32 + qtr * 8);
#pragma unroll
    for (int j = 0; j < 8; j++) {
      q0s[j] = (__bf16)((float)r0[j] * SC);
      q1s[j] = (__bf16)((float)r1[j] * SC);
    }
  }

  f32x4 o[4] = {};
  float m_ = -1e30f, l_ = 0.0f;
  const int nkt = 2 * qx + 2;

  gload_lds16(kSrcBase, kDst);
  gload_lds16(vSrcBase, vDst);
  __syncthreads();

  int buf = 0;
  for (int t = 0; t < nkt; t++) {
    const int k0 = t * 64;
    if (t + 1 < nkt) {
      const long koff = (long)(k0 + 64);
      gload_lds16(kSrcBase + koff * C_, kDst + (buf ^ 1) * bufStride);
      gload_lds16(vSrcBase + koff, vDst + (buf ^ 1) * bufStride);
    }
    if (k0 <= qwTop) {
      const __bf16* ks = Ks[buf];
      const __bf16* vs = Vs[buf];
      f32x4 sT[4] = {};
      __builtin_amdgcn_s_setprio(1);
#pragma unroll
      for (int kb = 0; kb < 4; kb++) {
        bf16x8 aK0 = *(const bf16x8*)&ks[(kb * 16 + l15) * 64 + ((qtr ^ (l15 & 7)) * 8)];
        bf16x8 aK1 = *(const bf16x8*)&ks[(kb * 16 + l15) * 64 + (((4 + qtr) ^ (l15 & 7)) * 8)];
        sT[kb] = __builtin_amdgcn_mfma_f32_16x16x32_bf16(aK0, q0s, sT[kb], 0, 0, 0);
        sT[kb] = __builtin_amdgcn_mfma_f32_16x16x32_bf16(aK1, q1s, sT[kb], 0, 0, 0);
      }
      __builtin_amdgcn_s_setprio(0);
      if (k0 + 63 > qw) {
#pragma unroll
        for (int kb = 0; kb < 4; kb++)
#pragma unroll
          for (int r = 0; r < 4; r++)
            if (k0 + kb * 16 + qtr * 4 + r > q_lane) sT[kb][r] = -1e30f;
      }
      float mx = -1e30f;
#pragma unroll
      for (int kb = 0; kb < 4; kb++)
#pragma unroll
        for (int r = 0; r < 4; r++) mx = fmaxf(mx, sT[kb][r]);
      mx = fmaxf(mx, __shfl_xor(mx, 16));
      mx = fmaxf(mx, __shfl_xor(mx, 32));
      const bool defer = __all(mx - m_ <= 8.0f);
      const float mnew = defer ? m_ : fmaxf(m_, mx);
      float psum = 0.0f;
#pragma unroll
      for (int kb = 0; kb < 4; kb++) {
        bf16x4 p4;
#pragma unroll
        for (int r = 0; r < 4; r++) {
          const float pv = exp2f(sT[kb][r] - mnew);
          psum += pv;
          p4[r] = (__bf16)pv;
        }
        *(bf16x4*)&psW[kb * 16] = p4;
      }
      psum += __shfl_xor(psum, 16);
      psum += __shfl_xor(psum, 32);
      if (defer) {
        l_ += psum;
      } else {
        const float fac = exp2f(m_ - mnew);
        l_ = l_ * fac + psum;
        m_ = mnew;
#pragma unroll
        for (int r = 0; r < 4; r++) {
          const float fr = __shfl(fac, (lane & 48) + qtr * 4 + r);
#pragma unroll
          for (int dg = 0; dg < 4; dg++) o[dg][r] *= fr;
        }
      }
      __builtin_amdgcn_s_setprio(1);
#pragma unroll
      for (int s = 0; s < 2; s++) {
        bf16x8 aP = *(const bf16x8*)&psR[s * 32];
#pragma unroll
        for (int dg = 0; dg < 4; dg++) {
          bf16x8 bV = *(const bf16x8*)&vs[(dg * 16 + l15) * 64 + (((s * 4 + qtr) ^ (l15 & 7)) * 8)];
          o[dg] = __builtin_amdgcn_mfma_f32_16x16x32_bf16(aP, bV, o[dg], 0, 0, 0);
        }
      }
      __builtin_amdgcn_s_setprio(0);
    }
    __syncthreads();
    buf ^= 1;
  }

  const float linv = 1.0f / l_;
#pragma unroll
  for (int r = 0; r < 4; r++) {
    const float lr = __shfl(linv, (lane & 48) + qtr * 4 + r);
    const long row = bT + qw + qtr * 4 + r;
#pragma unroll
    for (int dg = 0; dg < 4; dg++)
      O[row * C_ + h * 64 + dg * 16 + l15] = (__bf16)(o[dg][r] * lr);
  }
}

// ---------------- launch ----------------
extern "C" void kernel_launch(void* const* d_in, const int* in_sizes, int n_in,
                              void* d_out, int out_size, void* d_ws, size_t ws_size,
                              hipStream_t stream) {
  const float* x = (const float*)d_in[0];
  const float* wq = (const float*)d_in[1];
  const float* wk = (const float*)d_in[2];
  const float* wv = (const float*)d_in[3];
  const float* wproj = (const float*)d_in[4];
  const float* bproj = (const float*)d_in[5];
  const float* w1 = (const float*)d_in[6];
  const float* b1 = (const float*)d_in[7];
  const float* w2 = (const float*)d_in[8];
  const float* b2 = (const float*)d_in[9];
  const float* g1 = (const float*)d_in[10];
  const float* be1 = (const float*)d_in[11];
  const float* g2 = (const float*)d_in[12];
  const float* be2 = (const float*)d_in[13];

  char* ws = (char*)d_ws;
  const size_t MB = 1024ull * 1024ull;
  __bf16* h1 = (__bf16*)(ws + 0);          // 16MB; reused as att after QKV
  __bf16* Qb = (__bf16*)(ws + 16 * MB);    // 16MB; reused as h2 after attn
  __bf16* Kb = (__bf16*)(ws + 32 * MB);    // 16MB
  __bf16* Vtg = (__bf16*)(ws + 48 * MB);   // 16MB, V pre-transposed [C][B*T]
  __bf16* ff1 = (__bf16*)(ws + 32 * MB);   // 64MB, aliases Kb/Vtg (dead after attn)
  __bf16* wqt = (__bf16*)(ws + 96 * MB);   // wqt/wkt/wvt contiguous => [3072][1024]
  __bf16* wkt = (__bf16*)(ws + 98 * MB);
  __bf16* wvt = (__bf16*)(ws + 100 * MB);
  __bf16* wpt = (__bf16*)(ws + 102 * MB);
  __bf16* w1t = (__bf16*)(ws + 104 * MB);  // 8MB
  __bf16* w2t = (__bf16*)(ws + 112 * MB);  // 8MB
  __bf16* att = h1;
  __bf16* h2 = Qb;
  float* xout = (float*)d_out;

  dim3 tb(32, 8);
  transpose_f32_bf16<<<dim3(2, 32, 16), tb, 0, stream>>>(wq, wqt, 1024, 64, 1024 * 64, 64 * 1024);
  transpose_f32_bf16<<<dim3(2, 32, 16), tb, 0, stream>>>(wk, wkt, 1024, 64, 1024 * 64, 64 * 1024);
  transpose_f32_bf16<<<dim3(2, 32, 16), tb, 0, stream>>>(wv, wvt, 1024, 64, 1024 * 64, 64 * 1024);
  transpose_f32_bf16<<<dim3(32, 32, 1), tb, 0, stream>>>(wproj, wpt, 1024, 1024, 0, 0);
  transpose_f32_bf16<<<dim3(128, 32, 1), tb, 0, stream>>>(w1, w1t, 1024, 4096, 0, 0);
  transpose_f32_bf16<<<dim3(32, 128, 1), tb, 0, stream>>>(w2, w2t, 4096, 1024, 0, 0);

  ln_fwd<<<8192, 256, 0, stream>>>(x, g1, be1, h1);
  // fused QKV: Bt = [wqt|wkt|wvt] = [3072][1024]; 64 m-blocks x 12 n-blocks
  gemm1p<1><<<768, 512, 0, stream>>>(h1, wqt, Qb, Kb, Vtg, nullptr, nullptr, 8192, 3072, 1024, 768);
  attn_fwd2<<<dim3(64, 16), 512, 0, stream>>>(Qb, Kb, Vtg, att);
  gemm1p<2><<<256, 512, 0, stream>>>(att, wpt, xout, nullptr, nullptr, bproj, x, 8192, 1024, 1024, 256);
  ln_fwd<<<8192, 256, 0, stream>>>(xout, g2, be2, h2);
  gemm1p<0><<<1024, 512, 0, stream>>>(h2, w1t, ff1, nullptr, nullptr, b1, nullptr, 8192, 4096, 1024, 1024);
  gemm1p<2><<<256, 512, 0, stream>>>(ff1, w2t, xout, nullptr, nullptr, b2, (const float*)xout, 8192, 1024, 4096, 256);
}